// Round 1
// baseline (8389.815 us; speedup 1.0000x reference)
//
#include <hip/hip_runtime.h>
#include <hip/hip_bf16.h>

// Sizes (fixed by the problem)
#define N_NODES   100000
#define IN_F      256
#define HID_F     128
#define OUT_F     64

// ---------------------------------------------------------------------------
// GEMM1: h1[N,128] = x[N,256] @ W1[256,128]   (fp32, vector ALU)
// Block: 256 threads handles 32 rows x 128 cols; thread tile 4x4.
// x tile staged in LDS (32x256 f32 = 32KB); W1 streamed from L2 (128KB, hot).
// ---------------------------------------------------------------------------
__global__ __launch_bounds__(256) void gemm1_kernel(const float* __restrict__ x,
                                                    const float* __restrict__ W1,
                                                    float* __restrict__ h1) {
    __shared__ float xs[32][IN_F];          // 32 KiB
    const int tid = threadIdx.x;
    const int block_row = blockIdx.x * 32;  // 100000 / 32 = 3125 exact

    // stage 32x256 floats = 2048 float4; 8 per thread, coalesced
    {
        const float4* xg = reinterpret_cast<const float4*>(x + (size_t)block_row * IN_F);
        float4* xsv = reinterpret_cast<float4*>(&xs[0][0]);
#pragma unroll
        for (int i = 0; i < 8; ++i) {
            int idx = tid + i * 256;
            xsv[idx] = xg[idx];
        }
    }
    __syncthreads();

    const int cg = tid & 31;   // col group: cols cg*4 .. cg*4+3  (32*4 = 128)
    const int rg = tid >> 5;   // row group: rows rg*4 .. rg*4+3  (8*4  = 32)

    float acc[4][4] = {};
#pragma unroll 4
    for (int k = 0; k < IN_F; ++k) {
        const float4 w = *reinterpret_cast<const float4*>(W1 + (size_t)k * HID_F + cg * 4);
#pragma unroll
        for (int r = 0; r < 4; ++r) {
            const float xv = xs[rg * 4 + r][k];
            acc[r][0] = fmaf(xv, w.x, acc[r][0]);
            acc[r][1] = fmaf(xv, w.y, acc[r][1]);
            acc[r][2] = fmaf(xv, w.z, acc[r][2]);
            acc[r][3] = fmaf(xv, w.w, acc[r][3]);
        }
    }

#pragma unroll
    for (int r = 0; r < 4; ++r) {
        float4 o = make_float4(acc[r][0], acc[r][1], acc[r][2], acc[r][3]);
        *reinterpret_cast<float4*>(h1 + (size_t)(block_row + rg * 4 + r) * HID_F + cg * 4) = o;
    }
}

// ---------------------------------------------------------------------------
// GEMM2: h2[N,64] = relu(agg1[N,128]) @ W2[128,64]
// Block: 256 threads handles 32 rows x 64 cols; thread tile 2x4.
// ReLU fused into the LDS staging load.
// ---------------------------------------------------------------------------
__global__ __launch_bounds__(256) void gemm2_kernel(const float* __restrict__ agg1,
                                                    const float* __restrict__ W2,
                                                    float* __restrict__ h2) {
    __shared__ float as_[32][HID_F];        // 16 KiB
    const int tid = threadIdx.x;
    const int block_row = blockIdx.x * 32;

    {
        const float4* ag = reinterpret_cast<const float4*>(agg1 + (size_t)block_row * HID_F);
        float4* asv = reinterpret_cast<float4*>(&as_[0][0]);
#pragma unroll
        for (int i = 0; i < 4; ++i) {
            float4 v = ag[tid + i * 256];
            v.x = fmaxf(v.x, 0.f); v.y = fmaxf(v.y, 0.f);
            v.z = fmaxf(v.z, 0.f); v.w = fmaxf(v.w, 0.f);
            asv[tid + i * 256] = v;
        }
    }
    __syncthreads();

    const int cg = tid & 15;   // cols cg*4 .. cg*4+3  (16*4 = 64)
    const int rg = tid >> 4;   // rows rg*2 .. rg*2+1  (16*2 = 32)

    float acc[2][4] = {};
#pragma unroll 4
    for (int k = 0; k < HID_F; ++k) {
        const float4 w = *reinterpret_cast<const float4*>(W2 + (size_t)k * OUT_F + cg * 4);
#pragma unroll
        for (int r = 0; r < 2; ++r) {
            const float xv = as_[rg * 2 + r][k];
            acc[r][0] = fmaf(xv, w.x, acc[r][0]);
            acc[r][1] = fmaf(xv, w.y, acc[r][1]);
            acc[r][2] = fmaf(xv, w.z, acc[r][2]);
            acc[r][3] = fmaf(xv, w.w, acc[r][3]);
        }
    }

#pragma unroll
    for (int r = 0; r < 2; ++r) {
        float4 o = make_float4(acc[r][0], acc[r][1], acc[r][2], acc[r][3]);
        *reinterpret_cast<float4*>(h2 + (size_t)(block_row + rg * 2 + r) * OUT_F + cg * 4) = o;
    }
}

// ---------------------------------------------------------------------------
// SpMM scatter-sum: out[dst[e]] += h[src[e]], feature width W (floats).
// Each edge is handled by L = W/4 lanes, each doing a float4 gather +
// 4 scalar fp32 atomics. Grid-stride over edges.
// ---------------------------------------------------------------------------
template <int W>
__global__ __launch_bounds__(256) void spmm_scatter_kernel(const float* __restrict__ h,
                                                           const int* __restrict__ src,
                                                           const int* __restrict__ dst,
                                                           float* __restrict__ out,
                                                           int n_edges) {
    constexpr int L = W / 4;
    const long long gid = (long long)blockIdx.x * blockDim.x + threadIdx.x;
    const int lane = (int)(gid % L);
    const long long total_threads = (long long)gridDim.x * blockDim.x;
    const int estride = (int)(total_threads / L);

    for (int e = (int)(gid / L); e < n_edges; e += estride) {
        const int s = src[e];
        const int d = dst[e];
        const float4 v = *reinterpret_cast<const float4*>(h + (size_t)s * W + lane * 4);
        float* o = out + (size_t)d * W + lane * 4;
        atomicAdd(o + 0, v.x);
        atomicAdd(o + 1, v.y);
        atomicAdd(o + 2, v.z);
        atomicAdd(o + 3, v.w);
    }
}

// ---------------------------------------------------------------------------
extern "C" void kernel_launch(void* const* d_in, const int* in_sizes, int n_in,
                              void* d_out, int out_size, void* d_ws, size_t ws_size,
                              hipStream_t stream) {
    const float* x    = (const float*)d_in[0];
    const int*   esrc = (const int*)d_in[1];
    const int*   edst = (const int*)d_in[2];
    const float* W1   = (const float*)d_in[3];
    const float* W2   = (const float*)d_in[4];
    float* out = (float*)d_out;

    const int n_edges = in_sizes[1];

    const size_t h1_bytes   = (size_t)N_NODES * HID_F * sizeof(float);  // 51.2 MB
    const size_t out_bytes  = (size_t)N_NODES * OUT_F * sizeof(float);  // 25.6 MB

    float* h1   = (float*)d_ws;                            // [N,128]
    float* agg1 = (float*)((char*)d_ws + h1_bytes);        // [N,128]
    float* h2   = h1;                                      // reuse h1's region: [N,64]

    // zero the accumulation buffers (ws/out are re-poisoned before every call)
    hipMemsetAsync(agg1, 0, h1_bytes, stream);
    hipMemsetAsync(out, 0, out_bytes, stream);

    // GEMM1: h1 = x @ W1
    gemm1_kernel<<<N_NODES / 32, 256, 0, stream>>>(x, W1, h1);

    // SpMM1: agg1[dst] += h1[src]   (width 128)
    spmm_scatter_kernel<HID_F><<<4096, 256, 0, stream>>>(h1, esrc, edst, agg1, n_edges);

    // GEMM2: h2 = relu(agg1) @ W2
    gemm2_kernel<<<N_NODES / 32, 256, 0, stream>>>(agg1, W2, h2);

    // SpMM2: out[dst] += h2[src]    (width 64)
    spmm_scatter_kernel<OUT_F><<<4096, 256, 0, stream>>>(h2, esrc, edst, out, n_edges);
}

// Round 3
// 1161.185 us; speedup vs baseline: 7.2252x; 7.2252x over previous
//
#include <hip/hip_runtime.h>
#include <hip/hip_bf16.h>

// Sizes (fixed by the problem)
#define N_NODES   100000
#define IN_F      256
#define HID_F     128
#define OUT_F     64

#define SCAN_CHUNK 512
#define NSCAN_BLK ((N_NODES + SCAN_CHUNK - 1) / SCAN_CHUNK)   // 196

// fp32 -> bf16 round-to-nearest-even (bit-exact, no intrinsic dependency)
__device__ __forceinline__ ushort f2bf(float f) {
    uint u = __float_as_uint(f);
    u += 0x7fffu + ((u >> 16) & 1u);
    return (ushort)(u >> 16);
}
__device__ __forceinline__ float bf2f_lo(uint u) { return __uint_as_float(u << 16); }
__device__ __forceinline__ float bf2f_hi(uint u) { return __uint_as_float(u & 0xffff0000u); }

// ---------------------------------------------------------------------------
// GEMM1: h1[N,128] = x[N,256] @ W1[256,128]   (fp32 compute, bf16 store)
// ---------------------------------------------------------------------------
__global__ __launch_bounds__(256) void gemm1_kernel(const float* __restrict__ x,
                                                    const float* __restrict__ W1,
                                                    ushort* __restrict__ h1) {
    __shared__ float xs[32][IN_F];          // 32 KiB
    const int tid = threadIdx.x;
    const int block_row = blockIdx.x * 32;  // 100000 / 32 = 3125 exact

    {
        const float4* xg = reinterpret_cast<const float4*>(x + (size_t)block_row * IN_F);
        float4* xsv = reinterpret_cast<float4*>(&xs[0][0]);
#pragma unroll
        for (int i = 0; i < 8; ++i) {
            int idx = tid + i * 256;
            xsv[idx] = xg[idx];
        }
    }
    __syncthreads();

    const int cg = tid & 31;   // cols cg*4 .. cg*4+3
    const int rg = tid >> 5;   // rows rg*4 .. rg*4+3

    float acc[4][4] = {};
#pragma unroll 4
    for (int k = 0; k < IN_F; ++k) {
        const float4 w = *reinterpret_cast<const float4*>(W1 + (size_t)k * HID_F + cg * 4);
#pragma unroll
        for (int r = 0; r < 4; ++r) {
            const float xv = xs[rg * 4 + r][k];
            acc[r][0] = fmaf(xv, w.x, acc[r][0]);
            acc[r][1] = fmaf(xv, w.y, acc[r][1]);
            acc[r][2] = fmaf(xv, w.z, acc[r][2]);
            acc[r][3] = fmaf(xv, w.w, acc[r][3]);
        }
    }

#pragma unroll
    for (int r = 0; r < 4; ++r) {
        uint2 o;
        o.x = ((uint)f2bf(acc[r][1]) << 16) | (uint)f2bf(acc[r][0]);
        o.y = ((uint)f2bf(acc[r][3]) << 16) | (uint)f2bf(acc[r][2]);
        *reinterpret_cast<uint2*>(h1 + (size_t)(block_row + rg * 4 + r) * HID_F + cg * 4) = o;
    }
}

// ---------------------------------------------------------------------------
// GEMM2: h2[N,64] = relu(agg1[N,128]) @ W2[128,64]   (bf16 in, bf16 out)
// ---------------------------------------------------------------------------
__global__ __launch_bounds__(256) void gemm2_kernel(const ushort* __restrict__ agg1,
                                                    const float* __restrict__ W2,
                                                    ushort* __restrict__ h2) {
    __shared__ float as_[32][HID_F];        // 16 KiB
    const int tid = threadIdx.x;
    const int block_row = blockIdx.x * 32;

    {
        const uint* ag = reinterpret_cast<const uint*>(agg1 + (size_t)block_row * HID_F);
        float* asf = &as_[0][0];
#pragma unroll
        for (int i = 0; i < 8; ++i) {
            int idx = tid + i * 256;          // 2048 uints = 32x128 bf16
            uint u = ag[idx];
            asf[2 * idx]     = fmaxf(bf2f_lo(u), 0.f);
            asf[2 * idx + 1] = fmaxf(bf2f_hi(u), 0.f);
        }
    }
    __syncthreads();

    const int cg = tid & 15;   // cols cg*4 .. cg*4+3
    const int rg = tid >> 4;   // rows rg*2 .. rg*2+1

    float acc[2][4] = {};
#pragma unroll 4
    for (int k = 0; k < HID_F; ++k) {
        const float4 w = *reinterpret_cast<const float4*>(W2 + (size_t)k * OUT_F + cg * 4);
#pragma unroll
        for (int r = 0; r < 2; ++r) {
            const float xv = as_[rg * 2 + r][k];
            acc[r][0] = fmaf(xv, w.x, acc[r][0]);
            acc[r][1] = fmaf(xv, w.y, acc[r][1]);
            acc[r][2] = fmaf(xv, w.z, acc[r][2]);
            acc[r][3] = fmaf(xv, w.w, acc[r][3]);
        }
    }

#pragma unroll
    for (int r = 0; r < 2; ++r) {
        uint2 o;
        o.x = ((uint)f2bf(acc[r][1]) << 16) | (uint)f2bf(acc[r][0]);
        o.y = ((uint)f2bf(acc[r][3]) << 16) | (uint)f2bf(acc[r][2]);
        *reinterpret_cast<uint2*>(h2 + (size_t)(block_row + rg * 2 + r) * OUT_F + cg * 4) = o;
    }
}

// ---------------------------------------------------------------------------
// CSR build: histogram -> 3-phase exclusive scan -> atomic-cursor fill
// ---------------------------------------------------------------------------
__global__ __launch_bounds__(256) void hist_kernel(const int* __restrict__ dst,
                                                   int* __restrict__ counts, int n_edges) {
    int i = blockIdx.x * blockDim.x + threadIdx.x;
    const int stride = gridDim.x * blockDim.x;
    for (; i < n_edges; i += stride) atomicAdd(&counts[dst[i]], 1);
}

__global__ __launch_bounds__(256) void scan_reduce(const int* __restrict__ counts,
                                                   int* __restrict__ partials, int n) {
    __shared__ int sm[256];
    const int base = blockIdx.x * SCAN_CHUNK;
    const int t = threadIdx.x;
    int v = 0;
    for (int i = t; i < SCAN_CHUNK; i += 256) {
        int idx = base + i;
        if (idx < n) v += counts[idx];
    }
    sm[t] = v;
    __syncthreads();
    for (int off = 128; off > 0; off >>= 1) {
        if (t < off) sm[t] += sm[t + off];
        __syncthreads();
    }
    if (t == 0) partials[blockIdx.x] = sm[0];
}

__global__ __launch_bounds__(256) void scan_partials(const int* __restrict__ partials,
                                                     int* __restrict__ blockoff, int n) {
    __shared__ int a[256], b[256];
    const int t = threadIdx.x;
    a[t] = (t < n) ? partials[t] : 0;
    __syncthreads();
    int* cur = a; int* nxt = b;
    for (int off = 1; off < 256; off <<= 1) {
        nxt[t] = cur[t] + (t >= off ? cur[t - off] : 0);
        __syncthreads();
        int* tmp = cur; cur = nxt; nxt = tmp;
    }
    if (t < n) blockoff[t] = (t > 0) ? cur[t - 1] : 0;
}

__global__ __launch_bounds__(256) void scan_final(const int* __restrict__ counts,
                                                  const int* __restrict__ blockoff,
                                                  int* __restrict__ row_ptr,
                                                  int* __restrict__ cursor,
                                                  int n, int n_edges) {
    __shared__ int a[SCAN_CHUNK], b[SCAN_CHUNK];
    const int base = blockIdx.x * SCAN_CHUNK;
    const int t = threadIdx.x;
    for (int i = t; i < SCAN_CHUNK; i += 256) {
        int idx = base + i;
        a[i] = (idx < n) ? counts[idx] : 0;
    }
    __syncthreads();
    int* cur = a; int* nxt = b;
    for (int off = 1; off < SCAN_CHUNK; off <<= 1) {
        for (int i = t; i < SCAN_CHUNK; i += 256)
            nxt[i] = cur[i] + (i >= off ? cur[i - off] : 0);
        __syncthreads();
        int* tmp = cur; cur = nxt; nxt = tmp;
    }
    const int boff = blockoff[blockIdx.x];
    for (int i = t; i < SCAN_CHUNK; i += 256) {
        int idx = base + i;
        if (idx < n) {
            int ex = boff + (i > 0 ? cur[i - 1] : 0);
            row_ptr[idx] = ex;
            cursor[idx]  = ex;
        }
    }
    if (blockIdx.x == 0 && t == 0) row_ptr[n] = n_edges;
}

__global__ __launch_bounds__(256) void fill_kernel(const int* __restrict__ src,
                                                   const int* __restrict__ dst,
                                                   int* __restrict__ cursor,
                                                   int* __restrict__ csr_src, int n_edges) {
    int i = blockIdx.x * blockDim.x + threadIdx.x;
    const int stride = gridDim.x * blockDim.x;
    for (; i < n_edges; i += stride) {
        int pos = atomicAdd(&cursor[dst[i]], 1);
        csr_src[pos] = src[i];
    }
}

// ---------------------------------------------------------------------------
// SpMM1 gather (W=128, bf16 in, bf16 out): one wave per dst node.
// Each lane owns 2 features (one uint = 2 bf16). fp32 accumulate.
// ---------------------------------------------------------------------------
__global__ __launch_bounds__(256) void spmm1_kernel(const ushort* __restrict__ h,
                                                    const int* __restrict__ row_ptr,
                                                    const int* __restrict__ csr_src,
                                                    ushort* __restrict__ outb,
                                                    int n_nodes) {
    const int wid = blockIdx.x * 4 + (threadIdx.x >> 6);
    const int lane = threadIdx.x & 63;
    if (wid >= n_nodes) return;

    const int beg = row_ptr[wid];
    const int end = row_ptr[wid + 1];

    float a0 = 0.f, a1 = 0.f;
    int j = beg;
    if (j + 1 < end) {
        int s0 = __builtin_amdgcn_readfirstlane(csr_src[j]);
        for (; j + 1 < end; j += 2) {
            int s1 = __builtin_amdgcn_readfirstlane(csr_src[j + 1]);
            int s2 = (j + 2 < end) ? __builtin_amdgcn_readfirstlane(csr_src[j + 2]) : 0;
            uint u0 = *reinterpret_cast<const uint*>(h + (size_t)s0 * HID_F + lane * 2);
            uint u1 = *reinterpret_cast<const uint*>(h + (size_t)s1 * HID_F + lane * 2);
            a0 += bf2f_lo(u0) + bf2f_lo(u1);
            a1 += bf2f_hi(u0) + bf2f_hi(u1);
            s0 = s2;
        }
    }
    for (; j < end; ++j) {
        int s = __builtin_amdgcn_readfirstlane(csr_src[j]);
        uint u = *reinterpret_cast<const uint*>(h + (size_t)s * HID_F + lane * 2);
        a0 += bf2f_lo(u);
        a1 += bf2f_hi(u);
    }

    *reinterpret_cast<uint*>(outb + (size_t)wid * HID_F + lane * 2) =
        ((uint)f2bf(a1) << 16) | (uint)f2bf(a0);
}

// ---------------------------------------------------------------------------
// SpMM2 gather (W=64, bf16 in, fp32 out): one wave per dst node, 1 feat/lane.
// ---------------------------------------------------------------------------
__global__ __launch_bounds__(256) void spmm2_kernel(const ushort* __restrict__ h,
                                                    const int* __restrict__ row_ptr,
                                                    const int* __restrict__ csr_src,
                                                    float* __restrict__ out,
                                                    int n_nodes) {
    const int wid = blockIdx.x * 4 + (threadIdx.x >> 6);
    const int lane = threadIdx.x & 63;
    if (wid >= n_nodes) return;

    const int beg = row_ptr[wid];
    const int end = row_ptr[wid + 1];

    float a = 0.f;
    int j = beg;
    if (j + 1 < end) {
        int s0 = __builtin_amdgcn_readfirstlane(csr_src[j]);
        for (; j + 1 < end; j += 2) {
            int s1 = __builtin_amdgcn_readfirstlane(csr_src[j + 1]);
            int s2 = (j + 2 < end) ? __builtin_amdgcn_readfirstlane(csr_src[j + 2]) : 0;
            ushort u0 = h[(size_t)s0 * OUT_F + lane];
            ushort u1 = h[(size_t)s1 * OUT_F + lane];
            a += __uint_as_float((uint)u0 << 16) + __uint_as_float((uint)u1 << 16);
            s0 = s2;
        }
    }
    for (; j < end; ++j) {
        int s = __builtin_amdgcn_readfirstlane(csr_src[j]);
        ushort u = h[(size_t)s * OUT_F + lane];
        a += __uint_as_float((uint)u << 16);
    }

    out[(size_t)wid * OUT_F + lane] = a;
}

// ---------------------------------------------------------------------------
extern "C" void kernel_launch(void* const* d_in, const int* in_sizes, int n_in,
                              void* d_out, int out_size, void* d_ws, size_t ws_size,
                              hipStream_t stream) {
    const float* x    = (const float*)d_in[0];
    const int*   esrc = (const int*)d_in[1];
    const int*   edst = (const int*)d_in[2];
    const float* W1   = (const float*)d_in[3];
    const float* W2   = (const float*)d_in[4];
    float* out = (float*)d_out;

    const int n_edges = in_sizes[1];

    // workspace layout — total ~65.2 MB (round-1-proven budget was 102.4 MB)
    const size_t h1b = (size_t)N_NODES * HID_F * sizeof(ushort);   // 25.6 MB
    char* w = (char*)d_ws;
    ushort* h1   = (ushort*)w;               // [N,128] bf16
    ushort* agg1 = (ushort*)(w + h1b);       // [N,128] bf16
    ushort* h2   = h1;                       // [N,64] bf16, reuse (h1 dead after SpMM1)
    char* p = w + 2 * h1b;                   // 51.2 MB
    int* row_ptr  = (int*)p;  p += (((size_t)(N_NODES + 1) * 4 + 255) / 256) * 256;
    int* counts   = (int*)p;  p += (((size_t)N_NODES * 4 + 255) / 256) * 256;
    int* cursor   = (int*)p;  p += (((size_t)N_NODES * 4 + 255) / 256) * 256;
    int* blockoff = (int*)p;  p += 1024;
    int* partials = (int*)p;  p += 1024;
    int* csr_src  = (int*)p;                 // [E] ints, 12.8 MB

    // --- CSR build (shared by both SpMMs) ---
    hipMemsetAsync(counts, 0, (size_t)N_NODES * 4, stream);
    hist_kernel<<<2048, 256, 0, stream>>>(edst, counts, n_edges);
    scan_reduce<<<NSCAN_BLK, 256, 0, stream>>>(counts, partials, N_NODES);
    scan_partials<<<1, 256, 0, stream>>>(partials, blockoff, NSCAN_BLK);
    scan_final<<<NSCAN_BLK, 256, 0, stream>>>(counts, blockoff, row_ptr, cursor,
                                              N_NODES, n_edges);
    fill_kernel<<<2048, 256, 0, stream>>>(esrc, edst, cursor, csr_src, n_edges);

    // --- layer 1 ---
    gemm1_kernel<<<N_NODES / 32, 256, 0, stream>>>(x, W1, h1);
    spmm1_kernel<<<(N_NODES + 3) / 4, 256, 0, stream>>>(h1, row_ptr, csr_src,
                                                        agg1, N_NODES);
    // --- layer 2 ---
    gemm2_kernel<<<N_NODES / 32, 256, 0, stream>>>(agg1, W2, h2);
    spmm2_kernel<<<(N_NODES + 3) / 4, 256, 0, stream>>>(h2, row_ptr, csr_src,
                                                        out, N_NODES);
}

// Round 5
// 1019.160 us; speedup vs baseline: 8.2321x; 1.1394x over previous
//
#include <hip/hip_runtime.h>
#include <hip/hip_bf16.h>

// Sizes (fixed by the problem)
#define N_NODES   100000
#define IN_F      256
#define HID_F     128
#define OUT_F     64

#define SCAN_CHUNK 512
#define NSCAN_BLK ((N_NODES + SCAN_CHUNK - 1) / SCAN_CHUNK)   // 196

// fill partitioning: 8 dst-ranges (one per XCD), 12500 nodes each
#define NGROUP    8
#define GRANGE    (N_NODES / NGROUP)     // 12500
#define FILL_BLKS 2048                   // 256 blocks per group

// fp32 -> bf16 round-to-nearest-even
__device__ __forceinline__ ushort f2bf(float f) {
    uint u = __float_as_uint(f);
    u += 0x7fffu + ((u >> 16) & 1u);
    return (ushort)(u >> 16);
}
__device__ __forceinline__ float bf2f_lo(uint u) { return __uint_as_float(u << 16); }
__device__ __forceinline__ float bf2f_hi(uint u) { return __uint_as_float(u & 0xffff0000u); }

// ---------------------------------------------------------------------------
// GEMM1: h1[N,128] = x[N,256] @ W1[256,128]   (fp32 compute, bf16 store)
// ---------------------------------------------------------------------------
__global__ __launch_bounds__(256) void gemm1_kernel(const float* __restrict__ x,
                                                    const float* __restrict__ W1,
                                                    ushort* __restrict__ h1) {
    __shared__ float xs[32][IN_F];          // 32 KiB
    const int tid = threadIdx.x;
    const int block_row = blockIdx.x * 32;  // 100000 / 32 = 3125 exact

    {
        const float4* xg = reinterpret_cast<const float4*>(x + (size_t)block_row * IN_F);
        float4* xsv = reinterpret_cast<float4*>(&xs[0][0]);
#pragma unroll
        for (int i = 0; i < 8; ++i) {
            int idx = tid + i * 256;
            xsv[idx] = xg[idx];
        }
    }
    __syncthreads();

    const int cg = tid & 31;   // cols cg*4 .. cg*4+3
    const int rg = tid >> 5;   // rows rg*4 .. rg*4+3

    float acc[4][4] = {};
#pragma unroll 4
    for (int k = 0; k < IN_F; ++k) {
        const float4 w = *reinterpret_cast<const float4*>(W1 + (size_t)k * HID_F + cg * 4);
#pragma unroll
        for (int r = 0; r < 4; ++r) {
            const float xv = xs[rg * 4 + r][k];
            acc[r][0] = fmaf(xv, w.x, acc[r][0]);
            acc[r][1] = fmaf(xv, w.y, acc[r][1]);
            acc[r][2] = fmaf(xv, w.z, acc[r][2]);
            acc[r][3] = fmaf(xv, w.w, acc[r][3]);
        }
    }

#pragma unroll
    for (int r = 0; r < 4; ++r) {
        uint2 o;
        o.x = ((uint)f2bf(acc[r][1]) << 16) | (uint)f2bf(acc[r][0]);
        o.y = ((uint)f2bf(acc[r][3]) << 16) | (uint)f2bf(acc[r][2]);
        *reinterpret_cast<uint2*>(h1 + (size_t)(block_row + rg * 4 + r) * HID_F + cg * 4) = o;
    }
}

// ---------------------------------------------------------------------------
// GEMM2: h2[N,64] = relu(agg1[N,128]) @ W2[128,64]   (bf16 in, bf16 out)
// ---------------------------------------------------------------------------
__global__ __launch_bounds__(256) void gemm2_kernel(const ushort* __restrict__ agg1,
                                                    const float* __restrict__ W2,
                                                    ushort* __restrict__ h2) {
    __shared__ float as_[32][HID_F];        // 16 KiB
    const int tid = threadIdx.x;
    const int block_row = blockIdx.x * 32;

    {
        const uint* ag = reinterpret_cast<const uint*>(agg1 + (size_t)block_row * HID_F);
        float* asf = &as_[0][0];
#pragma unroll
        for (int i = 0; i < 8; ++i) {
            int idx = tid + i * 256;          // 2048 uints = 32x128 bf16
            uint u = ag[idx];
            asf[2 * idx]     = fmaxf(bf2f_lo(u), 0.f);
            asf[2 * idx + 1] = fmaxf(bf2f_hi(u), 0.f);
        }
    }
    __syncthreads();

    const int cg = tid & 15;   // cols cg*4 .. cg*4+3
    const int rg = tid >> 4;   // rows rg*2 .. rg*2+1

    float acc[2][4] = {};
#pragma unroll 4
    for (int k = 0; k < HID_F; ++k) {
        const float4 w = *reinterpret_cast<const float4*>(W2 + (size_t)k * OUT_F + cg * 4);
#pragma unroll
        for (int r = 0; r < 2; ++r) {
            const float xv = as_[rg * 2 + r][k];
            acc[r][0] = fmaf(xv, w.x, acc[r][0]);
            acc[r][1] = fmaf(xv, w.y, acc[r][1]);
            acc[r][2] = fmaf(xv, w.z, acc[r][2]);
            acc[r][3] = fmaf(xv, w.w, acc[r][3]);
        }
    }

#pragma unroll
    for (int r = 0; r < 2; ++r) {
        uint2 o;
        o.x = ((uint)f2bf(acc[r][1]) << 16) | (uint)f2bf(acc[r][0]);
        o.y = ((uint)f2bf(acc[r][3]) << 16) | (uint)f2bf(acc[r][2]);
        *reinterpret_cast<uint2*>(h2 + (size_t)(block_row + rg * 2 + r) * OUT_F + cg * 4) = o;
    }
}

// ---------------------------------------------------------------------------
// CSR build: histogram -> 3-phase exclusive scan -> XCD-partitioned fill
// ---------------------------------------------------------------------------
__global__ __launch_bounds__(256) void hist_kernel(const int* __restrict__ dst,
                                                   int* __restrict__ counts, int n_edges) {
    int i = blockIdx.x * blockDim.x + threadIdx.x;
    const int stride = gridDim.x * blockDim.x;
    for (; i < n_edges; i += stride) atomicAdd(&counts[dst[i]], 1);
}

__global__ __launch_bounds__(256) void scan_reduce(const int* __restrict__ counts,
                                                   int* __restrict__ partials, int n) {
    __shared__ int sm[256];
    const int base = blockIdx.x * SCAN_CHUNK;
    const int t = threadIdx.x;
    int v = 0;
    for (int i = t; i < SCAN_CHUNK; i += 256) {
        int idx = base + i;
        if (idx < n) v += counts[idx];
    }
    sm[t] = v;
    __syncthreads();
    for (int off = 128; off > 0; off >>= 1) {
        if (t < off) sm[t] += sm[t + off];
        __syncthreads();
    }
    if (t == 0) partials[blockIdx.x] = sm[0];
}

__global__ __launch_bounds__(256) void scan_partials(const int* __restrict__ partials,
                                                     int* __restrict__ blockoff, int n) {
    __shared__ int a[256], b[256];
    const int t = threadIdx.x;
    a[t] = (t < n) ? partials[t] : 0;
    __syncthreads();
    int* cur = a; int* nxt = b;
    for (int off = 1; off < 256; off <<= 1) {
        nxt[t] = cur[t] + (t >= off ? cur[t - off] : 0);
        __syncthreads();
        int* tmp = cur; cur = nxt; nxt = tmp;
    }
    if (t < n) blockoff[t] = (t > 0) ? cur[t - 1] : 0;
}

__global__ __launch_bounds__(256) void scan_final(const int* __restrict__ counts,
                                                  const int* __restrict__ blockoff,
                                                  int* __restrict__ row_ptr,
                                                  int* __restrict__ cursor,
                                                  int n, int n_edges) {
    __shared__ int a[SCAN_CHUNK], b[SCAN_CHUNK];
    const int base = blockIdx.x * SCAN_CHUNK;
    const int t = threadIdx.x;
    for (int i = t; i < SCAN_CHUNK; i += 256) {
        int idx = base + i;
        a[i] = (idx < n) ? counts[idx] : 0;
    }
    __syncthreads();
    int* cur = a; int* nxt = b;
    for (int off = 1; off < SCAN_CHUNK; off <<= 1) {
        for (int i = t; i < SCAN_CHUNK; i += 256)
            nxt[i] = cur[i] + (i >= off ? cur[i - off] : 0);
        __syncthreads();
        int* tmp = cur; cur = nxt; nxt = tmp;
    }
    const int boff = blockoff[blockIdx.x];
    for (int i = t; i < SCAN_CHUNK; i += 256) {
        int idx = base + i;
        if (idx < n) {
            int ex = boff + (i > 0 ? cur[i - 1] : 0);
            row_ptr[idx] = ex;
            cursor[idx]  = ex;
        }
    }
    if (blockIdx.x == 0 && t == 0) row_ptr[n] = n_edges;
}

// XCD-partitioned fill: block b handles dst range [(b&7)*GRANGE, +GRANGE).
// Keeps each XCD's dirty csr_src window at ~1.6 MB (fits 4 MB per-XCD L2),
// so scattered 4B stores accumulate in L2 instead of thrashing to HBM.
// Edge streams are nontemporal so they don't evict the dirty window.
__global__ __launch_bounds__(256) void fill_part_kernel(const int* __restrict__ src,
                                                        const int* __restrict__ dst,
                                                        int* __restrict__ cursor,
                                                        int* __restrict__ csr_src,
                                                        int n_edges) {
    const int g  = blockIdx.x & (NGROUP - 1);
    const int lb = blockIdx.x >> 3;                       // 0..255
    const int lo = g * GRANGE;
    const int hi = lo + GRANGE;
    const int stride = (FILL_BLKS / NGROUP) * 256;        // 65536
    for (int i = lb * 256 + threadIdx.x; i < n_edges; i += stride) {
        const int d = __builtin_nontemporal_load(dst + i);
        if (d >= lo && d < hi) {
            const int s = __builtin_nontemporal_load(src + i);
            const int pos = atomicAdd(&cursor[d], 1);
            csr_src[pos] = s;
        }
    }
}

// ---------------------------------------------------------------------------
// SpMM1 gather (W=128, bf16 in, bf16 out): one wave per dst node.
// ---------------------------------------------------------------------------
__global__ __launch_bounds__(256) void spmm1_kernel(const ushort* __restrict__ h,
                                                    const int* __restrict__ row_ptr,
                                                    const int* __restrict__ csr_src,
                                                    ushort* __restrict__ outb,
                                                    int n_nodes) {
    const int wid = blockIdx.x * 4 + (threadIdx.x >> 6);
    const int lane = threadIdx.x & 63;
    if (wid >= n_nodes) return;

    const int beg = row_ptr[wid];
    const int end = row_ptr[wid + 1];

    float a0 = 0.f, a1 = 0.f;
    int j = beg;
    if (j + 1 < end) {
        int s0 = __builtin_amdgcn_readfirstlane(csr_src[j]);
        for (; j + 1 < end; j += 2) {
            int s1 = __builtin_amdgcn_readfirstlane(csr_src[j + 1]);
            int s2 = (j + 2 < end) ? __builtin_amdgcn_readfirstlane(csr_src[j + 2]) : 0;
            uint u0 = *reinterpret_cast<const uint*>(h + (size_t)s0 * HID_F + lane * 2);
            uint u1 = *reinterpret_cast<const uint*>(h + (size_t)s1 * HID_F + lane * 2);
            a0 += bf2f_lo(u0) + bf2f_lo(u1);
            a1 += bf2f_hi(u0) + bf2f_hi(u1);
            s0 = s2;
        }
    }
    for (; j < end; ++j) {
        int s = __builtin_amdgcn_readfirstlane(csr_src[j]);
        uint u = *reinterpret_cast<const uint*>(h + (size_t)s * HID_F + lane * 2);
        a0 += bf2f_lo(u);
        a1 += bf2f_hi(u);
    }

    *reinterpret_cast<uint*>(outb + (size_t)wid * HID_F + lane * 2) =
        ((uint)f2bf(a1) << 16) | (uint)f2bf(a0);
}

// ---------------------------------------------------------------------------
// SpMM2 gather (W=64, bf16 in, fp32 out): one wave per dst node, 1 feat/lane.
// ---------------------------------------------------------------------------
__global__ __launch_bounds__(256) void spmm2_kernel(const ushort* __restrict__ h,
                                                    const int* __restrict__ row_ptr,
                                                    const int* __restrict__ csr_src,
                                                    float* __restrict__ out,
                                                    int n_nodes) {
    const int wid = blockIdx.x * 4 + (threadIdx.x >> 6);
    const int lane = threadIdx.x & 63;
    if (wid >= n_nodes) return;

    const int beg = row_ptr[wid];
    const int end = row_ptr[wid + 1];

    float a = 0.f;
    int j = beg;
    if (j + 1 < end) {
        int s0 = __builtin_amdgcn_readfirstlane(csr_src[j]);
        for (; j + 1 < end; j += 2) {
            int s1 = __builtin_amdgcn_readfirstlane(csr_src[j + 1]);
            int s2 = (j + 2 < end) ? __builtin_amdgcn_readfirstlane(csr_src[j + 2]) : 0;
            ushort u0 = h[(size_t)s0 * OUT_F + lane];
            ushort u1 = h[(size_t)s1 * OUT_F + lane];
            a += __uint_as_float((uint)u0 << 16) + __uint_as_float((uint)u1 << 16);
            s0 = s2;
        }
    }
    for (; j < end; ++j) {
        int s = __builtin_amdgcn_readfirstlane(csr_src[j]);
        ushort u = h[(size_t)s * OUT_F + lane];
        a += __uint_as_float((uint)u << 16);
    }

    out[(size_t)wid * OUT_F + lane] = a;
}

// ---------------------------------------------------------------------------
extern "C" void kernel_launch(void* const* d_in, const int* in_sizes, int n_in,
                              void* d_out, int out_size, void* d_ws, size_t ws_size,
                              hipStream_t stream) {
    const float* x    = (const float*)d_in[0];
    const int*   esrc = (const int*)d_in[1];
    const int*   edst = (const int*)d_in[2];
    const float* W1   = (const float*)d_in[3];
    const float* W2   = (const float*)d_in[4];
    float* out = (float*)d_out;

    const int n_edges = in_sizes[1];

    // workspace layout — total ~65.2 MB (round-3-proven budget)
    const size_t h1b = (size_t)N_NODES * HID_F * sizeof(ushort);   // 25.6 MB
    char* w = (char*)d_ws;
    ushort* h1   = (ushort*)w;               // [N,128] bf16
    ushort* agg1 = (ushort*)(w + h1b);       // [N,128] bf16
    ushort* h2   = h1;                       // [N,64] bf16, reuse (h1 dead after SpMM1)
    char* p = w + 2 * h1b;                   // 51.2 MB
    int* row_ptr  = (int*)p;  p += (((size_t)(N_NODES + 1) * 4 + 255) / 256) * 256;
    int* counts   = (int*)p;  p += (((size_t)N_NODES * 4 + 255) / 256) * 256;
    int* cursor   = (int*)p;  p += (((size_t)N_NODES * 4 + 255) / 256) * 256;
    int* blockoff = (int*)p;  p += 1024;
    int* partials = (int*)p;  p += 1024;
    int* csr_src  = (int*)p;                 // [E] ints, 12.8 MB

    // --- CSR build (shared by both SpMMs) ---
    hipMemsetAsync(counts, 0, (size_t)N_NODES * 4, stream);
    hist_kernel<<<2048, 256, 0, stream>>>(edst, counts, n_edges);
    scan_reduce<<<NSCAN_BLK, 256, 0, stream>>>(counts, partials, N_NODES);
    scan_partials<<<1, 256, 0, stream>>>(partials, blockoff, NSCAN_BLK);
    scan_final<<<NSCAN_BLK, 256, 0, stream>>>(counts, blockoff, row_ptr, cursor,
                                              N_NODES, n_edges);
    fill_part_kernel<<<FILL_BLKS, 256, 0, stream>>>(esrc, edst, cursor, csr_src, n_edges);

    // --- layer 1 ---
    gemm1_kernel<<<N_NODES / 32, 256, 0, stream>>>(x, W1, h1);
    spmm1_kernel<<<(N_NODES + 3) / 4, 256, 0, stream>>>(h1, row_ptr, csr_src,
                                                        agg1, N_NODES);
    // --- layer 2 ---
    gemm2_kernel<<<N_NODES / 32, 256, 0, stream>>>(agg1, W2, h2);
    spmm2_kernel<<<(N_NODES + 3) / 4, 256, 0, stream>>>(h2, row_ptr, csr_src,
                                                        out, N_NODES);
}

// Round 6
// 774.219 us; speedup vs baseline: 10.8365x; 1.3164x over previous
//
#include <hip/hip_runtime.h>
#include <hip/hip_bf16.h>

// Sizes (fixed by the problem)
#define N_NODES   100000
#define IN_F      256
#define HID_F     128
#define OUT_F     64

#define SCAN_CHUNK 512
#define NSCAN_BLK ((N_NODES + SCAN_CHUNK - 1) / SCAN_CHUNK)   // 196

// fill partitioning: 8 dst-ranges (one per XCD), 12500 nodes each
#define NGROUP    8
#define GRANGE    (N_NODES / NGROUP)     // 12500
#define FILL_BLKS 2048                   // 256 blocks per group

// fp32 -> bf16 round-to-nearest-even
__device__ __forceinline__ ushort f2bf(float f) {
    uint u = __float_as_uint(f);
    u += 0x7fffu + ((u >> 16) & 1u);
    return (ushort)(u >> 16);
}
__device__ __forceinline__ float bf2f_lo(uint u) { return __uint_as_float(u << 16); }
__device__ __forceinline__ float bf2f_hi(uint u) { return __uint_as_float(u & 0xffff0000u); }

// ---------------------------------------------------------------------------
// GEMM1: h1[N,128] = x[N,256] @ W1[256,128]   (fp32 compute, bf16 store)
// ---------------------------------------------------------------------------
__global__ __launch_bounds__(256) void gemm1_kernel(const float* __restrict__ x,
                                                    const float* __restrict__ W1,
                                                    ushort* __restrict__ h1) {
    __shared__ float xs[32][IN_F];          // 32 KiB
    const int tid = threadIdx.x;
    const int block_row = blockIdx.x * 32;  // 100000 / 32 = 3125 exact

    {
        const float4* xg = reinterpret_cast<const float4*>(x + (size_t)block_row * IN_F);
        float4* xsv = reinterpret_cast<float4*>(&xs[0][0]);
#pragma unroll
        for (int i = 0; i < 8; ++i) {
            int idx = tid + i * 256;
            xsv[idx] = xg[idx];
        }
    }
    __syncthreads();

    const int cg = tid & 31;   // cols cg*4 .. cg*4+3
    const int rg = tid >> 5;   // rows rg*4 .. rg*4+3

    float acc[4][4] = {};
#pragma unroll 4
    for (int k = 0; k < IN_F; ++k) {
        const float4 w = *reinterpret_cast<const float4*>(W1 + (size_t)k * HID_F + cg * 4);
#pragma unroll
        for (int r = 0; r < 4; ++r) {
            const float xv = xs[rg * 4 + r][k];
            acc[r][0] = fmaf(xv, w.x, acc[r][0]);
            acc[r][1] = fmaf(xv, w.y, acc[r][1]);
            acc[r][2] = fmaf(xv, w.z, acc[r][2]);
            acc[r][3] = fmaf(xv, w.w, acc[r][3]);
        }
    }

#pragma unroll
    for (int r = 0; r < 4; ++r) {
        uint2 o;
        o.x = ((uint)f2bf(acc[r][1]) << 16) | (uint)f2bf(acc[r][0]);
        o.y = ((uint)f2bf(acc[r][3]) << 16) | (uint)f2bf(acc[r][2]);
        *reinterpret_cast<uint2*>(h1 + (size_t)(block_row + rg * 4 + r) * HID_F + cg * 4) = o;
    }
}

// ---------------------------------------------------------------------------
// GEMM2: h2[N,64] = relu(agg1[N,128]) @ W2[128,64]   (bf16 in, bf16 out)
// ---------------------------------------------------------------------------
__global__ __launch_bounds__(256) void gemm2_kernel(const ushort* __restrict__ agg1,
                                                    const float* __restrict__ W2,
                                                    ushort* __restrict__ h2) {
    __shared__ float as_[32][HID_F];        // 16 KiB
    const int tid = threadIdx.x;
    const int block_row = blockIdx.x * 32;

    {
        const uint* ag = reinterpret_cast<const uint*>(agg1 + (size_t)block_row * HID_F);
        float* asf = &as_[0][0];
#pragma unroll
        for (int i = 0; i < 8; ++i) {
            int idx = tid + i * 256;          // 2048 uints = 32x128 bf16
            uint u = ag[idx];
            asf[2 * idx]     = fmaxf(bf2f_lo(u), 0.f);
            asf[2 * idx + 1] = fmaxf(bf2f_hi(u), 0.f);
        }
    }
    __syncthreads();

    const int cg = tid & 15;   // cols cg*4 .. cg*4+3
    const int rg = tid >> 4;   // rows rg*2 .. rg*2+1

    float acc[2][4] = {};
#pragma unroll 4
    for (int k = 0; k < HID_F; ++k) {
        const float4 w = *reinterpret_cast<const float4*>(W2 + (size_t)k * OUT_F + cg * 4);
#pragma unroll
        for (int r = 0; r < 2; ++r) {
            const float xv = as_[rg * 2 + r][k];
            acc[r][0] = fmaf(xv, w.x, acc[r][0]);
            acc[r][1] = fmaf(xv, w.y, acc[r][1]);
            acc[r][2] = fmaf(xv, w.z, acc[r][2]);
            acc[r][3] = fmaf(xv, w.w, acc[r][3]);
        }
    }

#pragma unroll
    for (int r = 0; r < 2; ++r) {
        uint2 o;
        o.x = ((uint)f2bf(acc[r][1]) << 16) | (uint)f2bf(acc[r][0]);
        o.y = ((uint)f2bf(acc[r][3]) << 16) | (uint)f2bf(acc[r][2]);
        *reinterpret_cast<uint2*>(h2 + (size_t)(block_row + rg * 2 + r) * OUT_F + cg * 4) = o;
    }
}

// ---------------------------------------------------------------------------
// CSR build: histogram -> 3-phase exclusive scan -> XCD-partitioned fill
// ---------------------------------------------------------------------------
__global__ __launch_bounds__(256) void hist_kernel(const int* __restrict__ dst,
                                                   int* __restrict__ counts, int n_edges) {
    int i = blockIdx.x * blockDim.x + threadIdx.x;
    const int stride = gridDim.x * blockDim.x;
    for (; i < n_edges; i += stride) atomicAdd(&counts[dst[i]], 1);
}

__global__ __launch_bounds__(256) void scan_reduce(const int* __restrict__ counts,
                                                   int* __restrict__ partials, int n) {
    __shared__ int sm[256];
    const int base = blockIdx.x * SCAN_CHUNK;
    const int t = threadIdx.x;
    int v = 0;
    for (int i = t; i < SCAN_CHUNK; i += 256) {
        int idx = base + i;
        if (idx < n) v += counts[idx];
    }
    sm[t] = v;
    __syncthreads();
    for (int off = 128; off > 0; off >>= 1) {
        if (t < off) sm[t] += sm[t + off];
        __syncthreads();
    }
    if (t == 0) partials[blockIdx.x] = sm[0];
}

__global__ __launch_bounds__(256) void scan_partials(const int* __restrict__ partials,
                                                     int* __restrict__ blockoff, int n) {
    __shared__ int a[256], b[256];
    const int t = threadIdx.x;
    a[t] = (t < n) ? partials[t] : 0;
    __syncthreads();
    int* cur = a; int* nxt = b;
    for (int off = 1; off < 256; off <<= 1) {
        nxt[t] = cur[t] + (t >= off ? cur[t - off] : 0);
        __syncthreads();
        int* tmp = cur; cur = nxt; nxt = tmp;
    }
    if (t < n) blockoff[t] = (t > 0) ? cur[t - 1] : 0;
}

__global__ __launch_bounds__(256) void scan_final(const int* __restrict__ counts,
                                                  const int* __restrict__ blockoff,
                                                  int* __restrict__ row_ptr,
                                                  int* __restrict__ cursor,
                                                  int n, int n_edges) {
    __shared__ int a[SCAN_CHUNK], b[SCAN_CHUNK];
    const int base = blockIdx.x * SCAN_CHUNK;
    const int t = threadIdx.x;
    for (int i = t; i < SCAN_CHUNK; i += 256) {
        int idx = base + i;
        a[i] = (idx < n) ? counts[idx] : 0;
    }
    __syncthreads();
    int* cur = a; int* nxt = b;
    for (int off = 1; off < SCAN_CHUNK; off <<= 1) {
        for (int i = t; i < SCAN_CHUNK; i += 256)
            nxt[i] = cur[i] + (i >= off ? cur[i - off] : 0);
        __syncthreads();
        int* tmp = cur; cur = nxt; nxt = tmp;
    }
    const int boff = blockoff[blockIdx.x];
    for (int i = t; i < SCAN_CHUNK; i += 256) {
        int idx = base + i;
        if (idx < n) {
            int ex = boff + (i > 0 ? cur[i - 1] : 0);
            row_ptr[idx] = ex;
            cursor[idx]  = ex;
        }
    }
    if (blockIdx.x == 0 && t == 0) row_ptr[n] = n_edges;
}

// XCD-partitioned fill (proven round 5): block b handles dst range of 12500.
__global__ __launch_bounds__(256) void fill_part_kernel(const int* __restrict__ src,
                                                        const int* __restrict__ dst,
                                                        int* __restrict__ cursor,
                                                        int* __restrict__ csr_src,
                                                        int n_edges) {
    const int g  = blockIdx.x & (NGROUP - 1);
    const int lb = blockIdx.x >> 3;                       // 0..255
    const int lo = g * GRANGE;
    const int hi = lo + GRANGE;
    const int stride = (FILL_BLKS / NGROUP) * 256;        // 65536
    for (int i = lb * 256 + threadIdx.x; i < n_edges; i += stride) {
        const int d = __builtin_nontemporal_load(dst + i);
        if (d >= lo && d < hi) {
            const int s = __builtin_nontemporal_load(src + i);
            const int pos = atomicAdd(&cursor[d], 1);
            csr_src[pos] = s;
        }
    }
}

// ---------------------------------------------------------------------------
// SpMM1 gather (W=128 bf16): one wave per dst node, wave split in 2 halves.
// Each half (32 lanes x uint2 = 256 B) gathers one full row -> 2 edges per
// step, 4 per unrolled iteration. Scalarized indices; cross-half combine
// via shfl_xor(32) once per node.
// ---------------------------------------------------------------------------
__global__ __launch_bounds__(256) void spmm1_kernel(const ushort* __restrict__ h,
                                                    const int* __restrict__ row_ptr,
                                                    const int* __restrict__ csr_src,
                                                    ushort* __restrict__ outb,
                                                    int n_nodes) {
    const int wid = blockIdx.x * 4 + (threadIdx.x >> 6);
    const int lane = threadIdx.x & 63;
    if (wid >= n_nodes) return;
    const int half = lane >> 5;     // 0/1: which edge of the pair
    const int sub  = lane & 31;     // owns bf16 feats sub*4 .. sub*4+3

    const int beg = __builtin_amdgcn_readfirstlane(row_ptr[wid]);
    const int end = __builtin_amdgcn_readfirstlane(row_ptr[wid + 1]);

    float a0 = 0.f, a1 = 0.f, a2 = 0.f, a3 = 0.f;
    int j = beg;
#pragma unroll 2
    for (; j + 3 < end; j += 4) {
        const int s0 = __builtin_amdgcn_readfirstlane(csr_src[j + 0]);
        const int s1 = __builtin_amdgcn_readfirstlane(csr_src[j + 1]);
        const int s2 = __builtin_amdgcn_readfirstlane(csr_src[j + 2]);
        const int s3 = __builtin_amdgcn_readfirstlane(csr_src[j + 3]);
        const int sa = half ? s1 : s0;
        const int sb = half ? s3 : s2;
        const uint2 u = *reinterpret_cast<const uint2*>(h + (size_t)sa * HID_F + sub * 4);
        const uint2 v = *reinterpret_cast<const uint2*>(h + (size_t)sb * HID_F + sub * 4);
        a0 += bf2f_lo(u.x) + bf2f_lo(v.x);
        a1 += bf2f_hi(u.x) + bf2f_hi(v.x);
        a2 += bf2f_lo(u.y) + bf2f_lo(v.y);
        a3 += bf2f_hi(u.y) + bf2f_hi(v.y);
    }
    if (j + 1 < end) {
        const int s0 = __builtin_amdgcn_readfirstlane(csr_src[j + 0]);
        const int s1 = __builtin_amdgcn_readfirstlane(csr_src[j + 1]);
        const int sa = half ? s1 : s0;
        const uint2 u = *reinterpret_cast<const uint2*>(h + (size_t)sa * HID_F + sub * 4);
        a0 += bf2f_lo(u.x); a1 += bf2f_hi(u.x);
        a2 += bf2f_lo(u.y); a3 += bf2f_hi(u.y);
        j += 2;
    }
    if (j < end && half == 0) {
        const int s = csr_src[j];
        const uint2 u = *reinterpret_cast<const uint2*>(h + (size_t)s * HID_F + sub * 4);
        a0 += bf2f_lo(u.x); a1 += bf2f_hi(u.x);
        a2 += bf2f_lo(u.y); a3 += bf2f_hi(u.y);
    }

    // combine halves
    a0 += __shfl_xor(a0, 32);
    a1 += __shfl_xor(a1, 32);
    a2 += __shfl_xor(a2, 32);
    a3 += __shfl_xor(a3, 32);

    if (half == 0) {
        uint2 o;
        o.x = ((uint)f2bf(a1) << 16) | (uint)f2bf(a0);
        o.y = ((uint)f2bf(a3) << 16) | (uint)f2bf(a2);
        *reinterpret_cast<uint2*>(outb + (size_t)wid * HID_F + sub * 4) = o;
    }
}

// ---------------------------------------------------------------------------
// SpMM2 gather (W=64 bf16 in, fp32 out): one wave per dst node, 4 quarters.
// Each quarter (16 lanes x uint2 = 128 B) gathers one full row -> 4 edges
// per iteration. Combine via shfl_xor(16) + shfl_xor(32).
// ---------------------------------------------------------------------------
__global__ __launch_bounds__(256) void spmm2_kernel(const ushort* __restrict__ h,
                                                    const int* __restrict__ row_ptr,
                                                    const int* __restrict__ csr_src,
                                                    float* __restrict__ out,
                                                    int n_nodes) {
    const int wid = blockIdx.x * 4 + (threadIdx.x >> 6);
    const int lane = threadIdx.x & 63;
    if (wid >= n_nodes) return;
    const int q   = lane >> 4;      // 0..3: which edge of the quad
    const int sub = lane & 15;      // owns bf16 feats sub*4 .. sub*4+3

    const int beg = __builtin_amdgcn_readfirstlane(row_ptr[wid]);
    const int end = __builtin_amdgcn_readfirstlane(row_ptr[wid + 1]);

    float a0 = 0.f, a1 = 0.f, a2 = 0.f, a3 = 0.f;
    int j = beg;
#pragma unroll 2
    for (; j + 3 < end; j += 4) {
        const int s0 = __builtin_amdgcn_readfirstlane(csr_src[j + 0]);
        const int s1 = __builtin_amdgcn_readfirstlane(csr_src[j + 1]);
        const int s2 = __builtin_amdgcn_readfirstlane(csr_src[j + 2]);
        const int s3 = __builtin_amdgcn_readfirstlane(csr_src[j + 3]);
        const int sel01 = (q & 1) ? s1 : s0;
        const int sel23 = (q & 1) ? s3 : s2;
        const int sa    = (q & 2) ? sel23 : sel01;
        const uint2 u = *reinterpret_cast<const uint2*>(h + (size_t)sa * OUT_F + sub * 4);
        a0 += bf2f_lo(u.x); a1 += bf2f_hi(u.x);
        a2 += bf2f_lo(u.y); a3 += bf2f_hi(u.y);
    }
    {
        const int rem = end - j;            // 0..3
        if (q < rem) {
            const int s = csr_src[j + q];   // per-quarter vector load (once)
            const uint2 u = *reinterpret_cast<const uint2*>(h + (size_t)s * OUT_F + sub * 4);
            a0 += bf2f_lo(u.x); a1 += bf2f_hi(u.x);
            a2 += bf2f_lo(u.y); a3 += bf2f_hi(u.y);
        }
    }

    // combine the 4 quarters
    a0 += __shfl_xor(a0, 16); a1 += __shfl_xor(a1, 16);
    a2 += __shfl_xor(a2, 16); a3 += __shfl_xor(a3, 16);
    a0 += __shfl_xor(a0, 32); a1 += __shfl_xor(a1, 32);
    a2 += __shfl_xor(a2, 32); a3 += __shfl_xor(a3, 32);

    if (q == 0) {
        float4 o = make_float4(a0, a1, a2, a3);
        *reinterpret_cast<float4*>(out + (size_t)wid * OUT_F + sub * 4) = o;
    }
}

// ---------------------------------------------------------------------------
extern "C" void kernel_launch(void* const* d_in, const int* in_sizes, int n_in,
                              void* d_out, int out_size, void* d_ws, size_t ws_size,
                              hipStream_t stream) {
    const float* x    = (const float*)d_in[0];
    const int*   esrc = (const int*)d_in[1];
    const int*   edst = (const int*)d_in[2];
    const float* W1   = (const float*)d_in[3];
    const float* W2   = (const float*)d_in[4];
    float* out = (float*)d_out;

    const int n_edges = in_sizes[1];

    // workspace layout — total ~65.2 MB (round-3-proven budget)
    const size_t h1b = (size_t)N_NODES * HID_F * sizeof(ushort);   // 25.6 MB
    char* w = (char*)d_ws;
    ushort* h1   = (ushort*)w;               // [N,128] bf16
    ushort* agg1 = (ushort*)(w + h1b);       // [N,128] bf16
    ushort* h2   = h1;                       // [N,64] bf16, reuse (h1 dead after SpMM1)
    char* p = w + 2 * h1b;                   // 51.2 MB
    int* row_ptr  = (int*)p;  p += (((size_t)(N_NODES + 1) * 4 + 255) / 256) * 256;
    int* counts   = (int*)p;  p += (((size_t)N_NODES * 4 + 255) / 256) * 256;
    int* cursor   = (int*)p;  p += (((size_t)N_NODES * 4 + 255) / 256) * 256;
    int* blockoff = (int*)p;  p += 1024;
    int* partials = (int*)p;  p += 1024;
    int* csr_src  = (int*)p;                 // [E] ints, 12.8 MB

    // --- CSR build (shared by both SpMMs) ---
    hipMemsetAsync(counts, 0, (size_t)N_NODES * 4, stream);
    hist_kernel<<<2048, 256, 0, stream>>>(edst, counts, n_edges);
    scan_reduce<<<NSCAN_BLK, 256, 0, stream>>>(counts, partials, N_NODES);
    scan_partials<<<1, 256, 0, stream>>>(partials, blockoff, NSCAN_BLK);
    scan_final<<<NSCAN_BLK, 256, 0, stream>>>(counts, blockoff, row_ptr, cursor,
                                              N_NODES, n_edges);
    fill_part_kernel<<<FILL_BLKS, 256, 0, stream>>>(esrc, edst, cursor, csr_src, n_edges);

    // --- layer 1 ---
    gemm1_kernel<<<N_NODES / 32, 256, 0, stream>>>(x, W1, h1);
    spmm1_kernel<<<(N_NODES + 3) / 4, 256, 0, stream>>>(h1, row_ptr, csr_src,
                                                        agg1, N_NODES);
    // --- layer 2 ---
    gemm2_kernel<<<N_NODES / 32, 256, 0, stream>>>(agg1, W2, h2);
    spmm2_kernel<<<(N_NODES + 3) / 4, 256, 0, stream>>>(h2, row_ptr, csr_src,
                                                        out, N_NODES);
}

// Round 7
// 691.160 us; speedup vs baseline: 12.1387x; 1.1202x over previous
//
#include <hip/hip_runtime.h>
#include <hip/hip_bf16.h>

// Sizes (fixed by the problem)
#define N_NODES   100000
#define IN_F      256
#define HID_F     128
#define OUT_F     64

#define SCAN_CHUNK 512
#define NSCAN_BLK ((N_NODES + SCAN_CHUNK - 1) / SCAN_CHUNK)   // 196

// fill partitioning: 8 dst-ranges (one per XCD), 12500 nodes each
#define NGROUP    8
#define GRANGE    (N_NODES / NGROUP)     // 12500
#define FILL_BLKS 2048                   // 256 blocks per group

typedef __attribute__((ext_vector_type(8))) short short8v;   // 8 bf16 (4 VGPR)
typedef __attribute__((ext_vector_type(4))) float f32x4;     // MFMA C/D

// fp32 -> bf16 round-to-nearest-even
__device__ __forceinline__ ushort f2bf(float f) {
    uint u = __float_as_uint(f);
    u += 0x7fffu + ((u >> 16) & 1u);
    return (ushort)(u >> 16);
}
__device__ __forceinline__ float bf2f_lo(uint u) { return __uint_as_float(u << 16); }
__device__ __forceinline__ float bf2f_hi(uint u) { return __uint_as_float(u & 0xffff0000u); }

// ---------------------------------------------------------------------------
// Weight prep: W1[256][128] -> W1T bf16 [128][256]; W2[128][64] -> W2T [64][128]
// Reads coalesced; scattered 2B writes land in L2 (tiny).
// ---------------------------------------------------------------------------
__global__ __launch_bounds__(256) void wtrans_kernel(const float* __restrict__ W1,
                                                     const float* __restrict__ W2,
                                                     ushort* __restrict__ w1t,
                                                     ushort* __restrict__ w2t) {
    const int b = blockIdx.x;
    if (b < 64) {                       // W1: 32768 elems, 512 per block
        const int base = b * 512;
        for (int e = base + threadIdx.x; e < base + 512; e += 256) {
            int k = e >> 7, c = e & 127;
            w1t[c * 256 + k] = f2bf(W1[e]);
        }
    } else {                            // W2: 8192 elems, 512 per block (16 blocks)
        const int base = (b - 64) * 512;
        for (int e = base + threadIdx.x; e < base + 512; e += 256) {
            int k = e >> 6, c = e & 63;
            w2t[c * 128 + k] = f2bf(W2[e]);
        }
    }
}

// ---------------------------------------------------------------------------
// GEMM1 (MFMA): h1[N,128] = x[N,256] @ W1, bf16 inputs, fp32 accum, bf16 out.
// Block = 64 rows (4 waves x 16); per wave: 8 col-tiles x 8 K-steps MFMA.
// A: per-lane 32B fp32 read (row=l&15, k=(l>>4)*8) converted in-register.
// B: per-lane 16B from W1T (L2-hot 64KB).  C/D: col=l&15, row=(l>>4)*4+reg.
// ---------------------------------------------------------------------------
__global__ __launch_bounds__(256) void gemm1_mfma(const float* __restrict__ x,
                                                  const ushort* __restrict__ w1t,
                                                  ushort* __restrict__ h1) {
    const int wid  = threadIdx.x >> 6;
    const int lane = threadIdx.x & 63;
    const int l15  = lane & 15;
    const int kgrp = lane >> 4;                       // 0..3
    const long base = (long)blockIdx.x * 64 + wid * 16;

    long arow = base + l15;
    if (arow > N_NODES - 1) arow = N_NODES - 1;       // tail clamp (stores guarded)
    const float* ap = x + arow * IN_F + kgrp * 8;

    f32x4 acc[8] = {};

#pragma unroll
    for (int ks = 0; ks < 8; ++ks) {
        const float4 af0 = *reinterpret_cast<const float4*>(ap + ks * 32);
        const float4 af1 = *reinterpret_cast<const float4*>(ap + ks * 32 + 4);
        short8v a;
        a[0] = (short)f2bf(af0.x); a[1] = (short)f2bf(af0.y);
        a[2] = (short)f2bf(af0.z); a[3] = (short)f2bf(af0.w);
        a[4] = (short)f2bf(af1.x); a[5] = (short)f2bf(af1.y);
        a[6] = (short)f2bf(af1.z); a[7] = (short)f2bf(af1.w);
#pragma unroll
        for (int ct = 0; ct < 8; ++ct) {
            const short8v bfr = *reinterpret_cast<const short8v*>(
                w1t + (size_t)(ct * 16 + l15) * 256 + ks * 32 + kgrp * 8);
            acc[ct] = __builtin_amdgcn_mfma_f32_16x16x32_bf16(a, bfr, acc[ct], 0, 0, 0);
        }
    }

#pragma unroll
    for (int ct = 0; ct < 8; ++ct)
#pragma unroll
        for (int r = 0; r < 4; ++r) {
            const long orow = base + kgrp * 4 + r;
            if (orow < N_NODES)
                h1[orow * HID_F + ct * 16 + l15] = f2bf(acc[ct][r]);
        }
}

// ---------------------------------------------------------------------------
// GEMM2 (MFMA): h2[N,64] = relu(agg1[N,128]) @ W2. A already bf16 (agg1);
// ReLU applied on the bf16 fragment (sign-bit test). Same structure, 4 ct x 4 ks.
// ---------------------------------------------------------------------------
__global__ __launch_bounds__(256) void gemm2_mfma(const ushort* __restrict__ agg1,
                                                  const ushort* __restrict__ w2t,
                                                  ushort* __restrict__ h2) {
    const int wid  = threadIdx.x >> 6;
    const int lane = threadIdx.x & 63;
    const int l15  = lane & 15;
    const int kgrp = lane >> 4;
    const long base = (long)blockIdx.x * 64 + wid * 16;

    long arow = base + l15;
    if (arow > N_NODES - 1) arow = N_NODES - 1;
    const ushort* ap = agg1 + arow * HID_F + kgrp * 8;

    f32x4 acc[4] = {};

#pragma unroll
    for (int ks = 0; ks < 4; ++ks) {
        short8v a = *reinterpret_cast<const short8v*>(ap + ks * 32);
#pragma unroll
        for (int i = 0; i < 8; ++i)
            if (a[i] < 0) a[i] = 0;      // bf16 relu via sign bit
#pragma unroll
        for (int ct = 0; ct < 4; ++ct) {
            const short8v bfr = *reinterpret_cast<const short8v*>(
                w2t + (size_t)(ct * 16 + l15) * 128 + ks * 32 + kgrp * 8);
            acc[ct] = __builtin_amdgcn_mfma_f32_16x16x32_bf16(a, bfr, acc[ct], 0, 0, 0);
        }
    }

#pragma unroll
    for (int ct = 0; ct < 4; ++ct)
#pragma unroll
        for (int r = 0; r < 4; ++r) {
            const long orow = base + kgrp * 4 + r;
            if (orow < N_NODES)
                h2[orow * OUT_F + ct * 16 + l15] = f2bf(acc[ct][r]);
        }
}

// ---------------------------------------------------------------------------
// CSR build: histogram -> 3-phase exclusive scan -> XCD-partitioned fill
// ---------------------------------------------------------------------------
__global__ __launch_bounds__(256) void hist_kernel(const int* __restrict__ dst,
                                                   int* __restrict__ counts, int n_edges) {
    int i = blockIdx.x * blockDim.x + threadIdx.x;
    const int stride = gridDim.x * blockDim.x;
    for (; i < n_edges; i += stride) atomicAdd(&counts[dst[i]], 1);
}

__global__ __launch_bounds__(256) void scan_reduce(const int* __restrict__ counts,
                                                   int* __restrict__ partials, int n) {
    __shared__ int sm[256];
    const int base = blockIdx.x * SCAN_CHUNK;
    const int t = threadIdx.x;
    int v = 0;
    for (int i = t; i < SCAN_CHUNK; i += 256) {
        int idx = base + i;
        if (idx < n) v += counts[idx];
    }
    sm[t] = v;
    __syncthreads();
    for (int off = 128; off > 0; off >>= 1) {
        if (t < off) sm[t] += sm[t + off];
        __syncthreads();
    }
    if (t == 0) partials[blockIdx.x] = sm[0];
}

__global__ __launch_bounds__(256) void scan_partials(const int* __restrict__ partials,
                                                     int* __restrict__ blockoff, int n) {
    __shared__ int a[256], b[256];
    const int t = threadIdx.x;
    a[t] = (t < n) ? partials[t] : 0;
    __syncthreads();
    int* cur = a; int* nxt = b;
    for (int off = 1; off < 256; off <<= 1) {
        nxt[t] = cur[t] + (t >= off ? cur[t - off] : 0);
        __syncthreads();
        int* tmp = cur; cur = nxt; nxt = tmp;
    }
    if (t < n) blockoff[t] = (t > 0) ? cur[t - 1] : 0;
}

__global__ __launch_bounds__(256) void scan_final(const int* __restrict__ counts,
                                                  const int* __restrict__ blockoff,
                                                  int* __restrict__ row_ptr,
                                                  int* __restrict__ cursor,
                                                  int n, int n_edges) {
    __shared__ int a[SCAN_CHUNK], b[SCAN_CHUNK];
    const int base = blockIdx.x * SCAN_CHUNK;
    const int t = threadIdx.x;
    for (int i = t; i < SCAN_CHUNK; i += 256) {
        int idx = base + i;
        a[i] = (idx < n) ? counts[idx] : 0;
    }
    __syncthreads();
    int* cur = a; int* nxt = b;
    for (int off = 1; off < SCAN_CHUNK; off <<= 1) {
        for (int i = t; i < SCAN_CHUNK; i += 256)
            nxt[i] = cur[i] + (i >= off ? cur[i - off] : 0);
        __syncthreads();
        int* tmp = cur; cur = nxt; nxt = tmp;
    }
    const int boff = blockoff[blockIdx.x];
    for (int i = t; i < SCAN_CHUNK; i += 256) {
        int idx = base + i;
        if (idx < n) {
            int ex = boff + (i > 0 ? cur[i - 1] : 0);
            row_ptr[idx] = ex;
            cursor[idx]  = ex;
        }
    }
    if (blockIdx.x == 0 && t == 0) row_ptr[n] = n_edges;
}

// XCD-partitioned fill (proven round 5): block b handles dst range of 12500.
__global__ __launch_bounds__(256) void fill_part_kernel(const int* __restrict__ src,
                                                        const int* __restrict__ dst,
                                                        int* __restrict__ cursor,
                                                        int* __restrict__ csr_src,
                                                        int n_edges) {
    const int g  = blockIdx.x & (NGROUP - 1);
    const int lb = blockIdx.x >> 3;                       // 0..255
    const int lo = g * GRANGE;
    const int hi = lo + GRANGE;
    const int stride = (FILL_BLKS / NGROUP) * 256;        // 65536
    for (int i = lb * 256 + threadIdx.x; i < n_edges; i += stride) {
        const int d = __builtin_nontemporal_load(dst + i);
        if (d >= lo && d < hi) {
            const int s = __builtin_nontemporal_load(src + i);
            const int pos = atomicAdd(&cursor[d], 1);
            csr_src[pos] = s;
        }
    }
}

// ---------------------------------------------------------------------------
// SpMM1 gather (W=128 bf16): one wave per dst node, split in 2 halves;
// each half (32 lanes x uint2 = 256B) gathers one row -> 4 edges/unrolled iter.
// ---------------------------------------------------------------------------
__global__ __launch_bounds__(256) void spmm1_kernel(const ushort* __restrict__ h,
                                                    const int* __restrict__ row_ptr,
                                                    const int* __restrict__ csr_src,
                                                    ushort* __restrict__ outb,
                                                    int n_nodes) {
    const int wid = blockIdx.x * 4 + (threadIdx.x >> 6);
    const int lane = threadIdx.x & 63;
    if (wid >= n_nodes) return;
    const int half = lane >> 5;
    const int sub  = lane & 31;

    const int beg = __builtin_amdgcn_readfirstlane(row_ptr[wid]);
    const int end = __builtin_amdgcn_readfirstlane(row_ptr[wid + 1]);

    float a0 = 0.f, a1 = 0.f, a2 = 0.f, a3 = 0.f;
    int j = beg;
#pragma unroll 2
    for (; j + 3 < end; j += 4) {
        const int s0 = __builtin_amdgcn_readfirstlane(csr_src[j + 0]);
        const int s1 = __builtin_amdgcn_readfirstlane(csr_src[j + 1]);
        const int s2 = __builtin_amdgcn_readfirstlane(csr_src[j + 2]);
        const int s3 = __builtin_amdgcn_readfirstlane(csr_src[j + 3]);
        const int sa = half ? s1 : s0;
        const int sb = half ? s3 : s2;
        const uint2 u = *reinterpret_cast<const uint2*>(h + (size_t)sa * HID_F + sub * 4);
        const uint2 v = *reinterpret_cast<const uint2*>(h + (size_t)sb * HID_F + sub * 4);
        a0 += bf2f_lo(u.x) + bf2f_lo(v.x);
        a1 += bf2f_hi(u.x) + bf2f_hi(v.x);
        a2 += bf2f_lo(u.y) + bf2f_lo(v.y);
        a3 += bf2f_hi(u.y) + bf2f_hi(v.y);
    }
    if (j + 1 < end) {
        const int s0 = __builtin_amdgcn_readfirstlane(csr_src[j + 0]);
        const int s1 = __builtin_amdgcn_readfirstlane(csr_src[j + 1]);
        const int sa = half ? s1 : s0;
        const uint2 u = *reinterpret_cast<const uint2*>(h + (size_t)sa * HID_F + sub * 4);
        a0 += bf2f_lo(u.x); a1 += bf2f_hi(u.x);
        a2 += bf2f_lo(u.y); a3 += bf2f_hi(u.y);
        j += 2;
    }
    if (j < end && half == 0) {
        const int s = csr_src[j];
        const uint2 u = *reinterpret_cast<const uint2*>(h + (size_t)s * HID_F + sub * 4);
        a0 += bf2f_lo(u.x); a1 += bf2f_hi(u.x);
        a2 += bf2f_lo(u.y); a3 += bf2f_hi(u.y);
    }

    a0 += __shfl_xor(a0, 32);
    a1 += __shfl_xor(a1, 32);
    a2 += __shfl_xor(a2, 32);
    a3 += __shfl_xor(a3, 32);

    if (half == 0) {
        uint2 o;
        o.x = ((uint)f2bf(a1) << 16) | (uint)f2bf(a0);
        o.y = ((uint)f2bf(a3) << 16) | (uint)f2bf(a2);
        *reinterpret_cast<uint2*>(outb + (size_t)wid * HID_F + sub * 4) = o;
    }
}

// ---------------------------------------------------------------------------
// SpMM2 gather (W=64 bf16 in, fp32 out): one wave per dst node, 4 quarters.
// ---------------------------------------------------------------------------
__global__ __launch_bounds__(256) void spmm2_kernel(const ushort* __restrict__ h,
                                                    const int* __restrict__ row_ptr,
                                                    const int* __restrict__ csr_src,
                                                    float* __restrict__ out,
                                                    int n_nodes) {
    const int wid = blockIdx.x * 4 + (threadIdx.x >> 6);
    const int lane = threadIdx.x & 63;
    if (wid >= n_nodes) return;
    const int q   = lane >> 4;
    const int sub = lane & 15;

    const int beg = __builtin_amdgcn_readfirstlane(row_ptr[wid]);
    const int end = __builtin_amdgcn_readfirstlane(row_ptr[wid + 1]);

    float a0 = 0.f, a1 = 0.f, a2 = 0.f, a3 = 0.f;
    int j = beg;
#pragma unroll 2
    for (; j + 3 < end; j += 4) {
        const int s0 = __builtin_amdgcn_readfirstlane(csr_src[j + 0]);
        const int s1 = __builtin_amdgcn_readfirstlane(csr_src[j + 1]);
        const int s2 = __builtin_amdgcn_readfirstlane(csr_src[j + 2]);
        const int s3 = __builtin_amdgcn_readfirstlane(csr_src[j + 3]);
        const int sel01 = (q & 1) ? s1 : s0;
        const int sel23 = (q & 1) ? s3 : s2;
        const int sa    = (q & 2) ? sel23 : sel01;
        const uint2 u = *reinterpret_cast<const uint2*>(h + (size_t)sa * OUT_F + sub * 4);
        a0 += bf2f_lo(u.x); a1 += bf2f_hi(u.x);
        a2 += bf2f_lo(u.y); a3 += bf2f_hi(u.y);
    }
    {
        const int rem = end - j;
        if (q < rem) {
            const int s = csr_src[j + q];
            const uint2 u = *reinterpret_cast<const uint2*>(h + (size_t)s * OUT_F + sub * 4);
            a0 += bf2f_lo(u.x); a1 += bf2f_hi(u.x);
            a2 += bf2f_lo(u.y); a3 += bf2f_hi(u.y);
        }
    }

    a0 += __shfl_xor(a0, 16); a1 += __shfl_xor(a1, 16);
    a2 += __shfl_xor(a2, 16); a3 += __shfl_xor(a3, 16);
    a0 += __shfl_xor(a0, 32); a1 += __shfl_xor(a1, 32);
    a2 += __shfl_xor(a2, 32); a3 += __shfl_xor(a3, 32);

    if (q == 0) {
        float4 o = make_float4(a0, a1, a2, a3);
        *reinterpret_cast<float4*>(out + (size_t)wid * OUT_F + sub * 4) = o;
    }
}

// ---------------------------------------------------------------------------
extern "C" void kernel_launch(void* const* d_in, const int* in_sizes, int n_in,
                              void* d_out, int out_size, void* d_ws, size_t ws_size,
                              hipStream_t stream) {
    const float* x    = (const float*)d_in[0];
    const int*   esrc = (const int*)d_in[1];
    const int*   edst = (const int*)d_in[2];
    const float* W1   = (const float*)d_in[3];
    const float* W2   = (const float*)d_in[4];
    float* out = (float*)d_out;

    const int n_edges = in_sizes[1];

    // workspace layout — total ~65.3 MB (round-3-proven budget)
    const size_t h1b = (size_t)N_NODES * HID_F * sizeof(ushort);   // 25.6 MB
    char* w = (char*)d_ws;
    ushort* h1   = (ushort*)w;               // [N,128] bf16
    ushort* agg1 = (ushort*)(w + h1b);       // [N,128] bf16
    ushort* h2   = h1;                       // [N,64] bf16, reuse
    char* p = w + 2 * h1b;                   // 51.2 MB
    int* row_ptr  = (int*)p;  p += (((size_t)(N_NODES + 1) * 4 + 255) / 256) * 256;
    int* counts   = (int*)p;  p += (((size_t)N_NODES * 4 + 255) / 256) * 256;
    int* cursor   = (int*)p;  p += (((size_t)N_NODES * 4 + 255) / 256) * 256;
    int* blockoff = (int*)p;  p += 1024;
    int* partials = (int*)p;  p += 1024;
    int* csr_src  = (int*)p;  p += (size_t)n_edges * 4;   // [E] ints, 12.8 MB
    ushort* w1t   = (ushort*)p;  p += 128 * 256 * 2;      // 64 KB
    ushort* w2t   = (ushort*)p;                           // 16 KB

    // --- weight prep + CSR build ---
    wtrans_kernel<<<80, 256, 0, stream>>>(W1, W2, w1t, w2t);
    hipMemsetAsync(counts, 0, (size_t)N_NODES * 4, stream);
    hist_kernel<<<2048, 256, 0, stream>>>(edst, counts, n_edges);
    scan_reduce<<<NSCAN_BLK, 256, 0, stream>>>(counts, partials, N_NODES);
    scan_partials<<<1, 256, 0, stream>>>(partials, blockoff, NSCAN_BLK);
    scan_final<<<NSCAN_BLK, 256, 0, stream>>>(counts, blockoff, row_ptr, cursor,
                                              N_NODES, n_edges);
    fill_part_kernel<<<FILL_BLKS, 256, 0, stream>>>(esrc, edst, cursor, csr_src, n_edges);

    const int gemm_blocks = (N_NODES + 63) / 64;   // 1563

    // --- layer 1 ---
    gemm1_mfma<<<gemm_blocks, 256, 0, stream>>>(x, w1t, h1);
    spmm1_kernel<<<(N_NODES + 3) / 4, 256, 0, stream>>>(h1, row_ptr, csr_src,
                                                        agg1, N_NODES);
    // --- layer 2 ---
    gemm2_mfma<<<gemm_blocks, 256, 0, stream>>>(agg1, w2t, h2);
    spmm2_kernel<<<(N_NODES + 3) / 4, 256, 0, stream>>>(h2, row_ptr, csr_src,
                                                        out, N_NODES);
}